// Round 5
// baseline (72.691 us; speedup 1.0000x reference)
//
#include <hip/hip_runtime.h>

// opool: x [B, D*C, h, w], D=12. Per (b,c) group of 12 contiguous 128x128 maps,
// output the map with the largest element (first-d tie-break == flat argmax
// first-occurrence). Fused single pass; winner fragment kept in LDS (manual
// register spill) so VGPR <= 64 -> 2 blocks/CU -> barrier bubbles overlap.
// Traffic: 402.7 MB read + 33.6 MB write.

typedef float f32x4 __attribute__((ext_vector_type(4)));

constexpr int D_ORI  = 12;
constexpr int HW     = 128 * 128;       // 16384 floats per map
constexpr int MAP_F4 = HW / 4;          // 4096 float4 per map
constexpr int GROUP  = D_ORI * HW;      // 196608 floats per group
constexpr int BLOCK  = 1024;            // 16 waves; thread owns 4 float4/map
constexpr int NW     = BLOCK / 64;      // 16

__device__ __forceinline__ float vmax16(f32x4 a, f32x4 b, f32x4 c, f32x4 d) {
    float m0 = fmaxf(fmaxf(a.x, a.y), fmaxf(a.z, a.w));
    float m1 = fmaxf(fmaxf(b.x, b.y), fmaxf(b.z, b.w));
    float m2 = fmaxf(fmaxf(c.x, c.y), fmaxf(c.z, c.w));
    float m3 = fmaxf(fmaxf(d.x, d.y), fmaxf(d.z, d.w));
    return fmaxf(fmaxf(m0, m1), fmaxf(m2, m3));
}

__global__ __launch_bounds__(BLOCK, 8) void opool_fused(const float* __restrict__ x,
                                                        float* __restrict__ out) {
    const int g = blockIdx.x;
    const f32x4* __restrict__ base =
        reinterpret_cast<const f32x4*>(x) + (size_t)g * (D_ORI * MAP_F4);
    const int tid  = threadIdx.x;
    const int wave = tid >> 6;
    const int lane = tid & 63;

    __shared__ float sred[D_ORI][NW];   // per-d slots: no WAR across iterations
    __shared__ f32x4 keep[BLOCK * 4];   // 64 KB: winner fragment, same-thread RW only

    f32x4 v0, v1, v2, v3;               // current map fragment
    f32x4 w0, w1, w2, w3;               // prefetched next map fragment
    float best = -__builtin_huge_valf();

    {   // load map 0
        const f32x4* p = base + tid;
        v0 = __builtin_nontemporal_load(p);
        v1 = __builtin_nontemporal_load(p + BLOCK);
        v2 = __builtin_nontemporal_load(p + 2 * BLOCK);
        v3 = __builtin_nontemporal_load(p + 3 * BLOCK);
    }

    #pragma unroll
    for (int d = 0; d < D_ORI; ++d) {
        // issue next map's loads BEFORE the reduce; lgkm-only barrier below
        // leaves them in flight (no vmcnt drain -> no HBM bubble)
        if (d + 1 < D_ORI) {
            const f32x4* p = base + (size_t)(d + 1) * MAP_F4 + tid;
            w0 = __builtin_nontemporal_load(p);
            w1 = __builtin_nontemporal_load(p + BLOCK);
            w2 = __builtin_nontemporal_load(p + 2 * BLOCK);
            w3 = __builtin_nontemporal_load(p + 3 * BLOCK);
        }

        float mv = vmax16(v0, v1, v2, v3);
        #pragma unroll
        for (int off = 32; off >= 1; off >>= 1)
            mv = fmaxf(mv, __shfl_xor(mv, off, 64));
        if (lane == 0) sred[d][wave] = mv;
        asm volatile("s_waitcnt lgkmcnt(0)" ::: "memory");
        __builtin_amdgcn_s_barrier();
        asm volatile("" ::: "memory");

        const f32x4* sr = reinterpret_cast<const f32x4*>(&sred[d][0]);
        f32x4 r0 = sr[0], r1 = sr[1], r2 = sr[2], r3 = sr[3];
        float gm = vmax16(r0, r1, r2, r3);

        if (gm > best) {                // block-uniform; strict > = first-d tie-break
            best = gm;
            keep[tid]             = v0; // manual spill: same-thread write/read,
            keep[tid + BLOCK]     = v1; // no barrier needed
            keep[tid + 2 * BLOCK] = v2;
            keep[tid + 3 * BLOCK] = v3;
        }
        if (d + 1 < D_ORI) { v0 = w0; v1 = w1; v2 = w2; v3 = w3; }
    }

    f32x4* o = reinterpret_cast<f32x4*>(out) + (size_t)g * MAP_F4 + tid;
    __builtin_nontemporal_store(keep[tid],             o);
    __builtin_nontemporal_store(keep[tid + BLOCK],     o + BLOCK);
    __builtin_nontemporal_store(keep[tid + 2 * BLOCK], o + 2 * BLOCK);
    __builtin_nontemporal_store(keep[tid + 3 * BLOCK], o + 3 * BLOCK);
}

extern "C" void kernel_launch(void* const* d_in, const int* in_sizes, int n_in,
                              void* d_out, int out_size, void* d_ws, size_t ws_size,
                              hipStream_t stream) {
    const float* x = (const float*)d_in[0];
    float* out     = (float*)d_out;
    const int ngroups = in_sizes[0] / GROUP;   // 512
    opool_fused<<<ngroups, BLOCK, 0, stream>>>(x, out);
}

// Round 6
// 70.741 us; speedup vs baseline: 1.0276x; 1.0276x over previous
//
#include <hip/hip_runtime.h>

// opool: x [B, D*C, h, w], D=12. Per (b,c) group of 12 contiguous 128x128 maps,
// output the map with the largest element (first-d tie-break == flat argmax
// first-occurrence). Fused single-pass: scan maps in order, keep the current
// winner's per-thread fragment in registers -> no winner re-read.
// Traffic: 402.7 MB read + 33.6 MB write = minimal. Measured 71.2 us
// (6.13 TB/s effective, ~97% of float4-copy ceiling). R5's 2-block/CU LDS-keep
// variant was 2% slower -> this register-keep form is the roofline config.

typedef float f32x4 __attribute__((ext_vector_type(4)));

constexpr int D_ORI  = 12;
constexpr int HW     = 128 * 128;       // 16384 floats per map
constexpr int MAP_F4 = HW / 4;          // 4096 float4 per map
constexpr int GROUP  = D_ORI * HW;      // 196608 floats per group
constexpr int BLOCK  = 1024;            // 16 waves; thread owns 4 float4/map
constexpr int NW     = BLOCK / 64;      // 16 waves

__device__ __forceinline__ float vmax16(f32x4 a, f32x4 b, f32x4 c, f32x4 d) {
    float m0 = fmaxf(fmaxf(a.x, a.y), fmaxf(a.z, a.w));
    float m1 = fmaxf(fmaxf(b.x, b.y), fmaxf(b.z, b.w));
    float m2 = fmaxf(fmaxf(c.x, c.y), fmaxf(c.z, c.w));
    float m3 = fmaxf(fmaxf(d.x, d.y), fmaxf(d.z, d.w));
    return fmaxf(fmaxf(m0, m1), fmaxf(m2, m3));
}

__global__ __launch_bounds__(BLOCK) void opool_fused(const float* __restrict__ x,
                                                     float* __restrict__ out) {
    const int g = blockIdx.x;
    const f32x4* __restrict__ base =
        reinterpret_cast<const f32x4*>(x) + (size_t)g * (D_ORI * MAP_F4);
    const int tid  = threadIdx.x;
    const int wave = tid >> 6;
    const int lane = tid & 63;

    __shared__ float sred[D_ORI][NW];   // per-d slots: no WAR across iterations

    f32x4 v0, v1, v2, v3;               // current map fragment
    f32x4 w0, w1, w2, w3;               // prefetched next map fragment
    f32x4 k0, k1, k2, k3;               // kept (winning) fragment
    float best = -__builtin_huge_valf();

    {   // load map 0
        const f32x4* p = base + tid;
        v0 = __builtin_nontemporal_load(p);
        v1 = __builtin_nontemporal_load(p + BLOCK);
        v2 = __builtin_nontemporal_load(p + 2 * BLOCK);
        v3 = __builtin_nontemporal_load(p + 3 * BLOCK);
    }
    k0 = v0; k1 = v1; k2 = v2; k3 = v3;

    #pragma unroll
    for (int d = 0; d < D_ORI; ++d) {
        // issue next map's loads BEFORE the reduce; the lgkm-only barrier
        // below leaves them in flight (no vmcnt drain -> no HBM bubble)
        if (d + 1 < D_ORI) {
            const f32x4* p = base + (size_t)(d + 1) * MAP_F4 + tid;
            w0 = __builtin_nontemporal_load(p);
            w1 = __builtin_nontemporal_load(p + BLOCK);
            w2 = __builtin_nontemporal_load(p + 2 * BLOCK);
            w3 = __builtin_nontemporal_load(p + 3 * BLOCK);
        }

        float mv = vmax16(v0, v1, v2, v3);
        #pragma unroll
        for (int off = 32; off >= 1; off >>= 1)
            mv = fmaxf(mv, __shfl_xor(mv, off, 64));
        if (lane == 0) sred[d][wave] = mv;
        asm volatile("s_waitcnt lgkmcnt(0)" ::: "memory");
        __builtin_amdgcn_s_barrier();
        asm volatile("" ::: "memory");

        float gm = sred[d][0];
        #pragma unroll
        for (int i = 1; i < NW; ++i) gm = fmaxf(gm, sred[d][i]);

        if (gm > best) {                // block-uniform; strict > = first-d tie-break
            best = gm;
            k0 = v0; k1 = v1; k2 = v2; k3 = v3;
        }
        if (d + 1 < D_ORI) { v0 = w0; v1 = w1; v2 = w2; v3 = w3; }
    }

    f32x4* o = reinterpret_cast<f32x4*>(out) + (size_t)g * MAP_F4 + tid;
    __builtin_nontemporal_store(k0, o);
    __builtin_nontemporal_store(k1, o + BLOCK);
    __builtin_nontemporal_store(k2, o + 2 * BLOCK);
    __builtin_nontemporal_store(k3, o + 3 * BLOCK);
}

extern "C" void kernel_launch(void* const* d_in, const int* in_sizes, int n_in,
                              void* d_out, int out_size, void* d_ws, size_t ws_size,
                              hipStream_t stream) {
    const float* x = (const float*)d_in[0];
    float* out     = (float*)d_out;
    const int ngroups = in_sizes[0] / GROUP;   // 512
    opool_fused<<<ngroups, BLOCK, 0, stream>>>(x, out);
}